// Round 6
// baseline (4385.206 us; speedup 1.0000x reference)
//
#include <hip/hip_runtime.h>

typedef unsigned short u16;
typedef __bf16 bf16x8_t __attribute__((ext_vector_type(8)));
typedef float f32x4_t __attribute__((ext_vector_type(4)));

__device__ __forceinline__ float bf2f(u16 u) {
    union { unsigned u; float f; } c; c.u = ((unsigned)u) << 16; return c.f;
}
__device__ __forceinline__ u16 f2bf(float f) {
    union { float f; unsigned u; } c; c.f = f;
    unsigned u = c.u;
    unsigned r = (u + 0x7FFFu + ((u >> 16) & 1u)) >> 16;
    return (u16)r;
}

__device__ __forceinline__ void block_sum2(float& s, float& sq) {
    for (int o = 32; o > 0; o >>= 1) { s += __shfl_xor(s, o); sq += __shfl_xor(sq, o); }
    __shared__ float sh[8];
    int wid = threadIdx.x >> 6;
    if ((threadIdx.x & 63) == 0) { sh[wid] = s; sh[4 + wid] = sq; }
    __syncthreads();
    s  = sh[0] + sh[1] + sh[2] + sh[3];
    sq = sh[4] + sh[5] + sh[6] + sh[7];
}

// ---- LN1 + window partition, per chunk: fp32 x -> bf16 window rows ---------
// blockIdx.x = local window row in chunk; global window row = row0 + local.
// Pad rows (gh/gw >= 64) written as zeros (reference pads AFTER LN).
__global__ __launch_bounds__(256) void ln1_window(
    const float* __restrict__ x, const float* __restrict__ w, const float* __restrict__ b,
    u16* __restrict__ out, int row0)
{
    int lrow = blockIdx.x, tid = threadIdx.x;
    int wr = row0 + lrow;
    int wb = wr / 196, t = wr % 196;
    int gh = ((wb % 25) / 5) * 14 + t / 14;
    int gw = (wb % 5) * 14 + t % 14;
    size_t orow = (size_t)lrow * 768;
    if (gh >= 64 || gw >= 64) {
        out[orow + tid] = 0; out[orow + tid + 256] = 0; out[orow + tid + 512] = 0;
        return;
    }
    size_t base = (size_t)(((wb / 25) * 64 + gh) * 64 + gw) * 768;
    float v0 = x[base + tid], v1 = x[base + tid + 256], v2 = x[base + tid + 512];
    float s = v0 + v1 + v2, sq = v0 * v0 + v1 * v1 + v2 * v2;
    block_sum2(s, sq);
    float mean = s * (1.0f / 768.0f);
    float var  = sq * (1.0f / 768.0f) - mean * mean;
    float inv  = rsqrtf(var + 1e-5f);
    out[orow + tid]       = f2bf((v0 - mean) * inv * w[tid]       + b[tid]);
    out[orow + tid + 256] = f2bf((v1 - mean) * inv * w[tid + 256] + b[tid + 256]);
    out[orow + tid + 512] = f2bf((v2 - mean) * inv * w[tid + 512] + b[tid + 512]);
}

// ---- LN2 chunk: fp32 x1 rows (pre-offset into d_out) -> bf16 ---------------
__global__ __launch_bounds__(256) void ln2_chunk(
    const float* __restrict__ xin, const float* __restrict__ w, const float* __restrict__ b,
    u16* __restrict__ out)
{
    int row = blockIdx.x, tid = threadIdx.x;
    size_t base = (size_t)row * 768;
    float v0 = xin[base + tid], v1 = xin[base + tid + 256], v2 = xin[base + tid + 512];
    float s = v0 + v1 + v2, sq = v0 * v0 + v1 * v1 + v2 * v2;
    block_sum2(s, sq);
    float mean = s * (1.0f / 768.0f);
    float var  = sq * (1.0f / 768.0f) - mean * mean;
    float inv  = rsqrtf(var + 1e-5f);
    out[base + tid]       = f2bf((v0 - mean) * inv * w[tid]       + b[tid]);
    out[base + tid + 256] = f2bf((v1 - mean) * inv * w[tid + 256] + b[tid + 256]);
    out[base + tid + 512] = f2bf((v2 - mean) * inv * w[tid + 512] + b[tid + 512]);
}

// ------------- weight transpose + cast: fp32 in[K][N] -> bf16 out[N][K] -----
__global__ __launch_bounds__(256) void transpose_wf(
    const float* __restrict__ in, u16* __restrict__ out, int K, int N)
{
    __shared__ u16 t[32][33];
    int n0 = blockIdx.x * 32, k0 = blockIdx.y * 32;
    int tx = threadIdx.x & 31, ty = threadIdx.x >> 5;
    for (int q = 0; q < 4; q++) {
        int k = k0 + ty + q * 8, n = n0 + tx;
        t[ty + q * 8][tx] = (k < K && n < N) ? f2bf(in[(size_t)k * N + n]) : (u16)0;
    }
    __syncthreads();
    for (int q = 0; q < 4; q++) {
        int n = n0 + ty + q * 8, k = k0 + tx;
        if (n < N && k < K) out[(size_t)n * K + k] = t[tx][ty + q * 8];
    }
}

// ---------------- fused attention: one block = (z, query-quarter) ----------
// grid (4, Wc*12), 64 threads. Per-thread exact fp32 online softmax over the
// full 196-key row; rel-pos bias in fp32; broadcast LDS reads of K/V rows.
__global__ __launch_bounds__(64) void attn_fused(
    const u16* __restrict__ qkvc, u16* __restrict__ attnc,
    const float* __restrict__ relH, const float* __restrict__ relW)
{
    int q0 = blockIdx.x * 49;
    int z  = blockIdx.y;
    int wb = z / 12, h = z % 12;
    int tid = threadIdx.x;

    __shared__ u16 Qs[49 * 64];       //  6272 B
    __shared__ u16 Ks[196 * 64];      // 25088 B (reused for V)
    __shared__ u16 Ss[49 * 200];      // 19600 B
    __shared__ float rel[49 * 29];    //  5684 B   (total 56,644 < 64 KiB)

    size_t base = (size_t)wb * 196 * 2304 + (size_t)h * 64;

    for (int idx = tid; idx < 49 * 8; idx += 64) {
        int r = idx >> 3, c8 = idx & 7;
        *(uint4*)&Qs[r * 64 + c8 * 8] =
            *(const uint4*)&qkvc[base + (size_t)(q0 + r) * 2304 + c8 * 8];
    }
    for (int idx = tid; idx < 196 * 8; idx += 64) {
        int r = idx >> 3, c8 = idx & 7;
        *(uint4*)&Ks[r * 64 + c8 * 8] =
            *(const uint4*)&qkvc[base + 768 + (size_t)r * 2304 + c8 * 8];
    }
    __syncthreads();

    // rel[q][j]: j<14 -> H term (kh=j), j>=14 -> W term (kw=j-14); UNSCALED q
    for (int idx = tid; idx < 49 * 28; idx += 64) {
        int ql = idx / 28, j = idx % 28;
        int qg = q0 + ql;
        int kk = (j < 14) ? j : (j - 14);
        int qi = (j < 14) ? (qg / 14) : (qg % 14);
        const float* R = ((j < 14) ? relH : relW) + (size_t)(qi - kk + 13) * 64;
        float d = 0.f;
        for (int c = 0; c < 64; c++) d += bf2f(Qs[ql * 64 + c]) * R[c];
        rel[ql * 29 + j] = d;
    }
    __syncthreads();

    float mx = -1e30f, sm = 0.f;
    if (tid < 49) {
        float Qr[64];
#pragma unroll
        for (int c8 = 0; c8 < 8; c8++) {
            uint4 v = *(const uint4*)&Qs[tid * 64 + c8 * 8];
            const u16* pv = (const u16*)&v;
#pragma unroll
            for (int j = 0; j < 8; j++) Qr[c8 * 8 + j] = bf2f(pv[j]);
        }
        for (int m = 0; m < 196; m++) {
            float d = 0.f;
#pragma unroll
            for (int c8 = 0; c8 < 8; c8++) {
                uint4 v = *(const uint4*)&Ks[m * 64 + c8 * 8];
                const u16* pv = (const u16*)&v;
#pragma unroll
                for (int j = 0; j < 8; j++) d += Qr[c8 * 8 + j] * bf2f(pv[j]);
            }
            float s = 0.125f * d + rel[tid * 29 + m / 14] + rel[tid * 29 + 14 + m % 14];
            Ss[tid * 200 + m] = f2bf(s);
            if (s > mx) { sm = sm * expf(mx - s) + 1.f; mx = s; }
            else        { sm += expf(s - mx); }
        }
    }
    __syncthreads();

    for (int idx = tid; idx < 196 * 8; idx += 64) {
        int r = idx >> 3, c8 = idx & 7;
        *(uint4*)&Ks[r * 64 + c8 * 8] =
            *(const uint4*)&qkvc[base + 1536 + (size_t)r * 2304 + c8 * 8];
    }
    __syncthreads();

    if (tid < 49) {
        float inv = 1.0f / sm;
        float Or[64];
#pragma unroll
        for (int c = 0; c < 64; c++) Or[c] = 0.f;
        for (int m = 0; m < 196; m++) {
            float p = expf(bf2f(Ss[tid * 200 + m]) - mx) * inv;
#pragma unroll
            for (int c8 = 0; c8 < 8; c8++) {
                uint4 v = *(const uint4*)&Ks[m * 64 + c8 * 8];
                const u16* pv = (const u16*)&v;
#pragma unroll
                for (int j = 0; j < 8; j++) Or[c8 * 8 + j] += p * bf2f(pv[j]);
            }
        }
        size_t ob = (size_t)(wb * 196 + q0 + tid) * 768 + (size_t)h * 64;
#pragma unroll
        for (int c = 0; c < 64; c++) attnc[ob + c] = f2bf(Or[c]);
    }
}

// ---------------- NT-mode MFMA bf16 GEMM, 128x128 tile, BK=32 ----------------
// MODE 0: qkv = lnw @ qkvT^T + bias            (bf16 out, Cb)
// MODE 3: proj — scatter window-row -> global row; Cf[g] = x_fp32[g]+acc+bias (fp32)
// MODE 4: fc1 + bias + exact gelu              (bf16 out, Cb)
// MODE 5: fc2 — Cf[idx] = xf[idx] + acc + bias (fp32 same-element RMW on d_out)
template <int MODE>
__global__ __launch_bounds__(256, 2) void gemm_nt(
    const u16* __restrict__ A, const u16* __restrict__ B,
    const float* __restrict__ bias, const float* xf,
    u16* __restrict__ Cb, float* Cf, int M, int row0)
{
    constexpr int BK = 32;
    constexpr int N   = (MODE == 0) ? 2304 : (MODE == 4) ? 3072 : 768;
    constexpr int K   = (MODE == 5) ? 3072 : 768;
    constexpr int lda = (MODE == 5) ? 3072 : 768;
    constexpr int ldb = K;

    __shared__ __align__(16) u16 As[128 * BK];
    __shared__ __align__(16) u16 Bs[128 * BK];

    int tid = threadIdx.x, wid = tid >> 6, lane = tid & 63;
    int quad = lane >> 4, l16 = lane & 15;
    int m_tile = blockIdx.y * 128, n_tile = blockIdx.x * 128;
    int wm0 = (wid >> 1) * 64, wn0 = (wid & 1) * 64;

    f32x4_t acc[4][4];
    f32x4_t z4 = {0.f, 0.f, 0.f, 0.f};
    for (int mt = 0; mt < 4; mt++)
        for (int nt = 0; nt < 4; nt++) acc[mt][nt] = z4;

    int rbase = wid * 32 + (lane >> 2);
    int kc = (lane & 3) * 8;
    const u16* aptr[2];
    const u16* bptr[2];
    int ldst[2];
    for (int i = 0; i < 2; i++) {
        int r = rbase + i * 16;
        int am = m_tile + r; if (am > M - 1) am = M - 1;
        int bn = n_tile + r; if (bn > N - 1) bn = N - 1;
        aptr[i] = A + (size_t)am * lda;
        bptr[i] = B + (size_t)bn * ldb;
        ldst[i] = r * BK + kc;
    }

    for (int k0 = 0; k0 < K; k0 += BK) {
        uint4 av[2], bv[2];
        for (int i = 0; i < 2; i++) {
            av[i] = *(const uint4*)(aptr[i] + k0 + kc);
            bv[i] = *(const uint4*)(bptr[i] + k0 + kc);
        }
        __syncthreads();
        for (int i = 0; i < 2; i++) {
            *(uint4*)&As[ldst[i]] = av[i];
            *(uint4*)&Bs[ldst[i]] = bv[i];
        }
        __syncthreads();
        bf16x8_t af[4], bfv[4];
        for (int t = 0; t < 4; t++) {
            af[t]  = *(const bf16x8_t*)&As[(wm0 + t * 16 + l16) * BK + quad * 8];
            bfv[t] = *(const bf16x8_t*)&Bs[(wn0 + t * 16 + l16) * BK + quad * 8];
        }
        for (int mt = 0; mt < 4; mt++)
            for (int nt = 0; nt < 4; nt++)
                acc[mt][nt] = __builtin_amdgcn_mfma_f32_16x16x32_bf16(
                    af[mt], bfv[nt], acc[mt][nt], 0, 0, 0);
    }

    // epilogue: C/D layout col=lane&15, row=quad*4+reg (m89/m91-verified)
    for (int mt = 0; mt < 4; mt++) {
        int rl = wm0 + mt * 16 + quad * 4;
        for (int nt = 0; nt < 4; nt++) {
            int col = n_tile + wn0 + nt * 16 + l16;
            if (col >= N) continue;
            for (int rg = 0; rg < 4; rg++) {
                int row = m_tile + rl + rg;
                if (row >= M) continue;
                float v = acc[mt][nt][rg];
                if constexpr (MODE == 0) {
                    Cb[(size_t)row * 2304 + col] = f2bf(v + bias[col]);
                } else if constexpr (MODE == 3) {
                    int wr = row0 + row;
                    int wb = wr / 196, t = wr % 196;
                    int gh = ((wb % 25) / 5) * 14 + t / 14;
                    int gw = (wb % 5) * 14 + t % 14;
                    if (gh < 64 && gw < 64) {
                        size_t g = (size_t)(((wb / 25) * 64 + gh) * 64 + gw) * 768 + col;
                        Cf[g] = xf[g] + v + bias[col];
                    }
                } else if constexpr (MODE == 4) {
                    float tt = v + bias[col];
                    Cb[(size_t)row * 3072 + col] =
                        f2bf(0.5f * tt * (1.0f + erff(tt * 0.70710678118f)));
                } else {
                    size_t idx = (size_t)(row0 + row) * 768 + col;
                    Cf[idx] = xf[idx] + v + bias[col];
                }
            }
        }
    }
}

extern "C" void kernel_launch(void* const* d_in, const int* in_sizes, int n_in,
                              void* d_out, int out_size, void* d_ws, size_t ws_size,
                              hipStream_t stream)
{
    (void)in_sizes; (void)n_in; (void)out_size;
    const float* x      = (const float*)d_in[0];
    const float* ln1_w  = (const float*)d_in[1];
    const float* ln1_b  = (const float*)d_in[2];
    const float* qkv_w  = (const float*)d_in[3];
    const float* qkv_b  = (const float*)d_in[4];
    const float* proj_w = (const float*)d_in[5];
    const float* proj_b = (const float*)d_in[6];
    const float* rel_h  = (const float*)d_in[7];
    const float* rel_w  = (const float*)d_in[8];
    const float* ln2_w  = (const float*)d_in[9];
    const float* ln2_b  = (const float*)d_in[10];
    const float* fc1_w  = (const float*)d_in[11];
    const float* fc1_b  = (const float*)d_in[12];
    const float* fc2_w  = (const float*)d_in[13];
    const float* fc2_b  = (const float*)d_in[14];

    // ---- ws layout: weights always at base, scratch above ----
    const size_t WT = 14155776ull;   // 13.5 MB
    char* ws = (char*)d_ws;
    u16* qkvT  = (u16*)ws;
    u16* projT = qkvT + 2304 * 768;
    u16* fc1T  = projT + 768 * 768;
    u16* fc2T  = fc1T + 3072 * 768;
    char* scratch = ws + WT;
    size_t avail = (ws_size > WT) ? (ws_size - WT) : 0;

    // attention scratch/window: lnw 301056 + qkv 903168 + attn 301056 = 1505280
    const size_t perW = 1505280ull;
    static const int wc_cand[9] = {100, 50, 25, 20, 10, 5, 4, 2, 1};
    int Wc = 1;
    for (int i = 0; i < 9; i++) {
        if ((size_t)wc_cand[i] * perW <= avail) { Wc = wc_cand[i]; break; }
    }
    // MLP scratch: xn2c Rm*768*2 + hbuf Rm*3072*2 = Rm*7680 B
    static const int rm_cand[8] = {16384, 8192, 4096, 2048, 1024, 512, 256, 128};
    int Rm = 128;
    for (int i = 0; i < 8; i++) {
        if ((size_t)rm_cand[i] * 7680ull <= avail) { Rm = rm_cand[i]; break; }
    }

    u16* lnwc  = (u16*)scratch;
    u16* qkvc  = (u16*)(scratch + (size_t)Wc * 301056ull);
    u16* attnc = (u16*)(scratch + (size_t)Wc * 1204224ull);
    u16* hbuf  = (u16*)scratch;                               // MLP overlays
    u16* xn2c  = (u16*)(scratch + (size_t)Rm * 6144ull);
    float* dout = (float*)d_out;                              // x1 lives here (fp32)

    transpose_wf<<<dim3(72, 24), 256, 0, stream>>>(qkv_w, qkvT, 768, 2304);
    transpose_wf<<<dim3(24, 24), 256, 0, stream>>>(proj_w, projT, 768, 768);
    transpose_wf<<<dim3(96, 24), 256, 0, stream>>>(fc1_w, fc1T, 768, 3072);
    transpose_wf<<<dim3(24, 96), 256, 0, stream>>>(fc2_w, fc2T, 3072, 768);

    int nch = 100 / Wc;
    int rows = Wc * 196;
    int gy = (rows + 127) / 128;
    for (int c = 0; c < nch; c++) {
        int r0 = c * rows;
        ln1_window<<<rows, 256, 0, stream>>>(x, ln1_w, ln1_b, lnwc, r0);
        gemm_nt<0><<<dim3(18, gy), 256, 0, stream>>>(
            lnwc, qkvT, qkv_b, nullptr, qkvc, nullptr, rows, 0);
        attn_fused<<<dim3(4, Wc * 12), 64, 0, stream>>>(qkvc, attnc, rel_h, rel_w);
        gemm_nt<3><<<dim3(6, gy), 256, 0, stream>>>(
            attnc, projT, proj_b, x, nullptr, dout, rows, r0);
    }

    int nm = 16384 / Rm;
    for (int c = 0; c < nm; c++) {
        int r0 = c * Rm;
        ln2_chunk<<<Rm, 256, 0, stream>>>(dout + (size_t)r0 * 768, ln2_w, ln2_b, xn2c);
        gemm_nt<4><<<dim3(24, Rm / 128), 256, 0, stream>>>(
            xn2c, fc1T, fc1_b, nullptr, hbuf, nullptr, Rm, 0);
        gemm_nt<5><<<dim3(6, Rm / 128), 256, 0, stream>>>(
            hbuf, fc2T, fc2_b, dout, nullptr, dout, Rm, r0);
    }
}

// Round 7
// 3144.551 us; speedup vs baseline: 1.3945x; 1.3945x over previous
//
#include <hip/hip_runtime.h>

typedef unsigned short u16;
typedef __bf16 bf16x8_t __attribute__((ext_vector_type(8)));
typedef float f32x4_t __attribute__((ext_vector_type(4)));

__device__ __forceinline__ float bf2f(u16 u) {
    union { unsigned u; float f; } c; c.u = ((unsigned)u) << 16; return c.f;
}
__device__ __forceinline__ u16 f2bf(float f) {
    union { float f; unsigned u; } c; c.f = f;
    unsigned u = c.u;
    unsigned r = (u + 0x7FFFu + ((u >> 16) & 1u)) >> 16;
    return (u16)r;
}

__device__ __forceinline__ void block_sum2(float& s, float& sq) {
    for (int o = 32; o > 0; o >>= 1) { s += __shfl_xor(s, o); sq += __shfl_xor(sq, o); }
    __shared__ float sh[8];
    int wid = threadIdx.x >> 6;
    if ((threadIdx.x & 63) == 0) { sh[wid] = s; sh[4 + wid] = sq; }
    __syncthreads();
    s  = sh[0] + sh[1] + sh[2] + sh[3];
    sq = sh[4] + sh[5] + sh[6] + sh[7];
}

// ---- LN1 + window partition, per chunk: fp32 x -> bf16 window rows ---------
__global__ __launch_bounds__(256) void ln1_window(
    const float* __restrict__ x, const float* __restrict__ w, const float* __restrict__ b,
    u16* __restrict__ out, int row0)
{
    int lrow = blockIdx.x, tid = threadIdx.x;
    int wr = row0 + lrow;
    int wb = wr / 196, t = wr % 196;
    int gh = ((wb % 25) / 5) * 14 + t / 14;
    int gw = (wb % 5) * 14 + t % 14;
    size_t orow = (size_t)lrow * 768;
    if (gh >= 64 || gw >= 64) {
        out[orow + tid] = 0; out[orow + tid + 256] = 0; out[orow + tid + 512] = 0;
        return;
    }
    size_t base = (size_t)(((wb / 25) * 64 + gh) * 64 + gw) * 768;
    float v0 = x[base + tid], v1 = x[base + tid + 256], v2 = x[base + tid + 512];
    float s = v0 + v1 + v2, sq = v0 * v0 + v1 * v1 + v2 * v2;
    block_sum2(s, sq);
    float mean = s * (1.0f / 768.0f);
    float var  = sq * (1.0f / 768.0f) - mean * mean;
    float inv  = rsqrtf(var + 1e-5f);
    out[orow + tid]       = f2bf((v0 - mean) * inv * w[tid]       + b[tid]);
    out[orow + tid + 256] = f2bf((v1 - mean) * inv * w[tid + 256] + b[tid + 256]);
    out[orow + tid + 512] = f2bf((v2 - mean) * inv * w[tid + 512] + b[tid + 512]);
}

// ---- LN2 chunk: fp32 x1 rows (pre-offset into d_out) -> bf16 ---------------
__global__ __launch_bounds__(256) void ln2_chunk(
    const float* __restrict__ xin, const float* __restrict__ w, const float* __restrict__ b,
    u16* __restrict__ out)
{
    int row = blockIdx.x, tid = threadIdx.x;
    size_t base = (size_t)row * 768;
    float v0 = xin[base + tid], v1 = xin[base + tid + 256], v2 = xin[base + tid + 512];
    float s = v0 + v1 + v2, sq = v0 * v0 + v1 * v1 + v2 * v2;
    block_sum2(s, sq);
    float mean = s * (1.0f / 768.0f);
    float var  = sq * (1.0f / 768.0f) - mean * mean;
    float inv  = rsqrtf(var + 1e-5f);
    out[base + tid]       = f2bf((v0 - mean) * inv * w[tid]       + b[tid]);
    out[base + tid + 256] = f2bf((v1 - mean) * inv * w[tid + 256] + b[tid + 256]);
    out[base + tid + 512] = f2bf((v2 - mean) * inv * w[tid + 512] + b[tid + 512]);
}

// ------------- weight transpose + cast: fp32 in[K][N] -> bf16 out[N][K] -----
__global__ __launch_bounds__(256) void transpose_wf(
    const float* __restrict__ in, u16* __restrict__ out, int K, int N)
{
    __shared__ u16 t[32][33];
    int n0 = blockIdx.x * 32, k0 = blockIdx.y * 32;
    int tx = threadIdx.x & 31, ty = threadIdx.x >> 5;
    for (int q = 0; q < 4; q++) {
        int k = k0 + ty + q * 8, n = n0 + tx;
        t[ty + q * 8][tx] = (k < K && n < N) ? f2bf(in[(size_t)k * N + n]) : (u16)0;
    }
    __syncthreads();
    for (int q = 0; q < 4; q++) {
        int n = n0 + ty + q * 8, k = k0 + tx;
        if (n < N && k < K) out[(size_t)n * K + k] = t[tx][ty + q * 8];
    }
}

// ------- build V^T per (local window, head): vt[z][d][m], m padded to 224 ---
__global__ __launch_bounds__(256) void build_vt(
    const u16* __restrict__ qkvc, u16* __restrict__ vt)
{
    int z = blockIdx.x;
    int wb = z / 12, h = z % 12;
    __shared__ u16 t[64][226];   // +2 pad: conflict-light transpose
    int tid = threadIdx.x;
    for (int base = 0; base < 196; base += 4) {
        int m = base + (tid >> 6);
        int d = tid & 63;
        t[d][m] = qkvc[(size_t)(wb * 196 + m) * 2304 + 1536 + h * 64 + d];
    }
    for (int idx = tid; idx < 28 * 64; idx += 256) {
        int m = 196 + idx / 64, d = idx % 64;
        t[d][m] = 0;
    }
    __syncthreads();
    size_t ob = (size_t)z * 64 * 224;
    for (int idx = tid; idx < 64 * 224; idx += 256) {
        int d = idx / 224, m = idx % 224;
        vt[ob + idx] = t[d][m];
    }
}

// ---------------- softmax + scale + decomposed rel-pos bias ----------------
// grid (196, Wc*12). S: [z][196][224] bf16; writes P in place, pad keys -> 0.
__global__ __launch_bounds__(256) void softmax_rel(
    const u16* __restrict__ qkvc, u16* __restrict__ S,
    const float* __restrict__ relH, const float* __restrict__ relW)
{
    int n = blockIdx.x;
    int z = blockIdx.y;
    int wb = z / 12, h = z % 12;
    int tid = threadIdx.x;
    __shared__ float qs[64];
    __shared__ float rel[28];
    __shared__ float red[8];
    size_t qbase = (size_t)(wb * 196 + n) * 2304 + h * 64;
    if (tid < 64) qs[tid] = bf2f(qkvc[qbase + tid]);
    __syncthreads();
    if (tid < 28) {
        int kk = tid % 14;
        bool isH = tid < 14;
        int qi = isH ? (n / 14) : (n % 14);
        const float* R = (isH ? relH : relW) + (size_t)(qi - kk + 13) * 64;
        float d = 0.f;
        for (int c = 0; c < 64; c++) d += qs[c] * R[c];
        rel[tid] = d;
    }
    __syncthreads();
    size_t srow = (size_t)z * 196 * 224 + (size_t)n * 224;
    int m = tid;
    bool valid = m < 196;
    float s;
    if (valid) s = 0.125f * bf2f(S[srow + m]) + rel[m / 14] + rel[14 + m % 14];
    else       s = -1e30f;
    float mx = s;
    for (int o = 32; o > 0; o >>= 1) mx = fmaxf(mx, __shfl_xor(mx, o));
    if ((tid & 63) == 0) red[tid >> 6] = mx;
    __syncthreads();
    mx = fmaxf(fmaxf(red[0], red[1]), fmaxf(red[2], red[3]));
    __syncthreads();
    float e = valid ? expf(s - mx) : 0.f;
    float sm = e;
    for (int o = 32; o > 0; o >>= 1) sm += __shfl_xor(sm, o);
    if ((tid & 63) == 0) red[4 + (tid >> 6)] = sm;
    __syncthreads();
    sm = red[4] + red[5] + red[6] + red[7];
    float p = e / sm;
    if (tid < 224) S[srow + tid] = f2bf(valid ? p : 0.f);
}

// ---------------- NT-mode MFMA bf16 GEMM, 128x128 tile, BK=32 ----------------
// MODE 0: qkv = lnw @ qkvT^T + bias              (bf16 out Cb)
// MODE 1: S = q k^T per (window,head), blockIdx.z (bf16 out Cb, ld 224)
// MODE 2: PV: P @ Vt^T -> attn channel block     (bf16 out Cb)
// MODE 3: proj — scatter window-row -> global; Cf[g] = x_fp32[g]+acc+bias (fp32)
// MODE 4: fc1 + bias + exact gelu                (bf16 out Cb)
// MODE 5: fc2 — Cf[idx] = xf[idx]+acc+bias       (fp32 d_out RMW)
template <int MODE>
__global__ __launch_bounds__(256, 2) void gemm_nt(
    const u16* __restrict__ Aall, const u16* __restrict__ Ball,
    const float* __restrict__ bias, const float* xf,
    u16* __restrict__ Cb, float* Cf, int M, int row0)
{
    constexpr int BK = 32;
    int N, K, lda, ldb;
    size_t aoff = 0, boff = 0, coff = 0;
    if constexpr (MODE == 0) { N = 2304; K = 768; lda = 768; ldb = 768; }
    else if constexpr (MODE == 1) {
        N = 196; K = 64; lda = 2304; ldb = 2304;
        int z = blockIdx.z;
        aoff = (size_t)(z / 12) * 196 * 2304 + (size_t)(z % 12) * 64;  // q
        boff = aoff + 768;                                             // k
        coff = (size_t)z * 196 * 224;
    } else if constexpr (MODE == 2) {
        N = 64; K = 224; lda = 224; ldb = 224;
        int z = blockIdx.z;
        aoff = (size_t)z * 196 * 224;                                  // P
        boff = (size_t)z * 64 * 224;                                   // V^T
        coff = (size_t)(z / 12) * 196 * 768 + (size_t)(z % 12) * 64;   // attn out
    } else if constexpr (MODE == 3) { N = 768; K = 768; lda = 768; ldb = 768; }
    else if constexpr (MODE == 4) { N = 3072; K = 768; lda = 768; ldb = 768; }
    else { N = 768; K = 3072; lda = 3072; ldb = 3072; }

    __shared__ __align__(16) u16 As[128 * BK];
    __shared__ __align__(16) u16 Bs[128 * BK];

    const u16* A = Aall + aoff;
    const u16* B = Ball + boff;
    int tid = threadIdx.x, wid = tid >> 6, lane = tid & 63;
    int quad = lane >> 4, l16 = lane & 15;
    int m_tile = blockIdx.y * 128, n_tile = blockIdx.x * 128;
    int wm0 = (wid >> 1) * 64, wn0 = (wid & 1) * 64;

    f32x4_t acc[4][4];
    f32x4_t z4 = {0.f, 0.f, 0.f, 0.f};
    for (int mt = 0; mt < 4; mt++)
        for (int nt = 0; nt < 4; nt++) acc[mt][nt] = z4;

    int rbase = wid * 32 + (lane >> 2);
    int kc = (lane & 3) * 8;
    const u16* aptr[2];
    const u16* bptr[2];
    int ldst[2];
    for (int i = 0; i < 2; i++) {
        int r = rbase + i * 16;
        int am = m_tile + r; if (am > M - 1) am = M - 1;
        int bn = n_tile + r; if (bn > N - 1) bn = N - 1;
        aptr[i] = A + (size_t)am * lda;
        bptr[i] = B + (size_t)bn * ldb;
        ldst[i] = r * BK + kc;
    }

    for (int k0 = 0; k0 < K; k0 += BK) {
        uint4 av[2], bv[2];
        for (int i = 0; i < 2; i++) {
            av[i] = *(const uint4*)(aptr[i] + k0 + kc);
            bv[i] = *(const uint4*)(bptr[i] + k0 + kc);
        }
        __syncthreads();
        for (int i = 0; i < 2; i++) {
            *(uint4*)&As[ldst[i]] = av[i];
            *(uint4*)&Bs[ldst[i]] = bv[i];
        }
        __syncthreads();
        bf16x8_t af[4], bfv[4];
        for (int t = 0; t < 4; t++) {
            af[t]  = *(const bf16x8_t*)&As[(wm0 + t * 16 + l16) * BK + quad * 8];
            bfv[t] = *(const bf16x8_t*)&Bs[(wn0 + t * 16 + l16) * BK + quad * 8];
        }
        for (int mt = 0; mt < 4; mt++)
            for (int nt = 0; nt < 4; nt++)
                acc[mt][nt] = __builtin_amdgcn_mfma_f32_16x16x32_bf16(
                    af[mt], bfv[nt], acc[mt][nt], 0, 0, 0);
    }

    // epilogue: C/D layout col=lane&15, row=quad*4+reg (m89/m91-verified)
    for (int mt = 0; mt < 4; mt++) {
        int rl = wm0 + mt * 16 + quad * 4;
        for (int nt = 0; nt < 4; nt++) {
            int col = n_tile + wn0 + nt * 16 + l16;
            if (col >= N) continue;
            for (int rg = 0; rg < 4; rg++) {
                int row = m_tile + rl + rg;
                if (row >= M) continue;
                float v = acc[mt][nt][rg];
                if constexpr (MODE == 0) {
                    Cb[(size_t)row * 2304 + col] = f2bf(v + bias[col]);
                } else if constexpr (MODE == 1) {
                    Cb[coff + (size_t)row * 224 + col] = f2bf(v);
                } else if constexpr (MODE == 2) {
                    Cb[coff + (size_t)row * 768 + col] = f2bf(v);
                } else if constexpr (MODE == 3) {
                    int wr = row0 + row;
                    int wb = wr / 196, t = wr % 196;
                    int gh = ((wb % 25) / 5) * 14 + t / 14;
                    int gw = (wb % 5) * 14 + t % 14;
                    if (gh < 64 && gw < 64) {
                        size_t g = (size_t)(((wb / 25) * 64 + gh) * 64 + gw) * 768 + col;
                        Cf[g] = xf[g] + v + bias[col];
                    }
                } else if constexpr (MODE == 4) {
                    float tt = v + bias[col];
                    Cb[(size_t)row * 3072 + col] =
                        f2bf(0.5f * tt * (1.0f + erff(tt * 0.70710678118f)));
                } else {
                    size_t idx = (size_t)(row0 + row) * 768 + col;
                    Cf[idx] = xf[idx] + v + bias[col];
                }
            }
        }
    }
}

extern "C" void kernel_launch(void* const* d_in, const int* in_sizes, int n_in,
                              void* d_out, int out_size, void* d_ws, size_t ws_size,
                              hipStream_t stream)
{
    (void)in_sizes; (void)n_in; (void)out_size;
    const float* x      = (const float*)d_in[0];
    const float* ln1_w  = (const float*)d_in[1];
    const float* ln1_b  = (const float*)d_in[2];
    const float* qkv_w  = (const float*)d_in[3];
    const float* qkv_b  = (const float*)d_in[4];
    const float* proj_w = (const float*)d_in[5];
    const float* proj_b = (const float*)d_in[6];
    const float* rel_h  = (const float*)d_in[7];
    const float* rel_w  = (const float*)d_in[8];
    const float* ln2_w  = (const float*)d_in[9];
    const float* ln2_b  = (const float*)d_in[10];
    const float* fc1_w  = (const float*)d_in[11];
    const float* fc1_b  = (const float*)d_in[12];
    const float* fc2_w  = (const float*)d_in[13];
    const float* fc2_b  = (const float*)d_in[14];

    // ---- ws layout: weights always at base, scratch above ----
    const size_t WT = 14155776ull;   // 13.5 MB
    char* ws = (char*)d_ws;
    u16* qkvT  = (u16*)ws;
    u16* projT = qkvT + 2304 * 768;
    u16* fc1T  = projT + 768 * 768;
    u16* fc2T  = fc1T + 3072 * 768;
    char* scratch = ws + WT;
    size_t avail = (ws_size > WT) ? (ws_size - WT) : 0;

    // per-window: lnw 301056 + qkv 903168 + S 1053696 + vt 344064 + attn 301056
    const size_t perW = 2903040ull;
    static const int wc_cand[9] = {100, 50, 25, 20, 10, 5, 4, 2, 1};
    int Wc = 1;
    for (int i = 0; i < 9; i++) {
        if ((size_t)wc_cand[i] * perW <= avail) { Wc = wc_cand[i]; break; }
    }
    static const int rm_cand[8] = {16384, 8192, 4096, 2048, 1024, 512, 256, 128};
    int Rm = 128;
    for (int i = 0; i < 8; i++) {
        if ((size_t)rm_cand[i] * 7680ull <= avail) { Rm = rm_cand[i]; break; }
    }

    u16* lnwc  = (u16*)scratch;
    u16* qkvc  = (u16*)(scratch + (size_t)Wc * 301056ull);
    u16* Sc    = (u16*)(scratch + (size_t)Wc * 1204224ull);
    u16* vtc   = (u16*)(scratch + (size_t)Wc * 2257920ull);
    u16* attnc = (u16*)(scratch + (size_t)Wc * 2601984ull);
    u16* hbuf  = (u16*)scratch;                               // MLP overlays
    u16* xn2c  = (u16*)(scratch + (size_t)Rm * 6144ull);
    float* dout = (float*)d_out;                              // x1 (fp32)

    transpose_wf<<<dim3(72, 24), 256, 0, stream>>>(qkv_w, qkvT, 768, 2304);
    transpose_wf<<<dim3(24, 24), 256, 0, stream>>>(proj_w, projT, 768, 768);
    transpose_wf<<<dim3(96, 24), 256, 0, stream>>>(fc1_w, fc1T, 768, 3072);
    transpose_wf<<<dim3(24, 96), 256, 0, stream>>>(fc2_w, fc2T, 3072, 768);

    int nch = 100 / Wc;
    int rows = Wc * 196;
    int gy = (rows + 127) / 128;
    for (int c = 0; c < nch; c++) {
        int r0 = c * rows;
        ln1_window<<<rows, 256, 0, stream>>>(x, ln1_w, ln1_b, lnwc, r0);
        gemm_nt<0><<<dim3(18, gy), 256, 0, stream>>>(
            lnwc, qkvT, qkv_b, nullptr, qkvc, nullptr, rows, 0);
        gemm_nt<1><<<dim3(2, 2, Wc * 12), 256, 0, stream>>>(
            qkvc, qkvc, nullptr, nullptr, Sc, nullptr, 196, 0);
        build_vt<<<Wc * 12, 256, 0, stream>>>(qkvc, vtc);
        softmax_rel<<<dim3(196, Wc * 12), 256, 0, stream>>>(qkvc, Sc, rel_h, rel_w);
        gemm_nt<2><<<dim3(1, 2, Wc * 12), 256, 0, stream>>>(
            Sc, vtc, nullptr, nullptr, attnc, nullptr, 196, 0);
        gemm_nt<3><<<dim3(6, gy), 256, 0, stream>>>(
            attnc, projT, proj_b, x, nullptr, dout, rows, r0);
    }

    int nm = 16384 / Rm;
    for (int c = 0; c < nm; c++) {
        int r0 = c * Rm;
        ln2_chunk<<<Rm, 256, 0, stream>>>(dout + (size_t)r0 * 768, ln2_w, ln2_b, xn2c);
        gemm_nt<4><<<dim3(24, Rm / 128), 256, 0, stream>>>(
            xn2c, fc1T, fc1_b, nullptr, hbuf, nullptr, Rm, 0);
        gemm_nt<5><<<dim3(6, Rm / 128), 256, 0, stream>>>(
            hbuf, fc2T, fc2_b, dout, nullptr, dout, Rm, r0);
    }
}